// Round 1
// baseline (3396.778 us; speedup 1.0000x reference)
//
#include <hip/hip_runtime.h>
#include <cmath>

#define BB 2
#define SS 2048
#define DMODEL 1024
#define NHEADS 16
#define DK 64
#define BSR (BB*SS)          // 4096 rows

// ---------------------------------------------------------------------------
// GEMM (fp32):  C[M,N] = A[M,K] @ W[N,K]^T  (+ optional bias[N])
// 128x128 tile, BK=16, 256 threads, 8x8 microtile.
// ---------------------------------------------------------------------------
#define GBM 128
#define GBN 128
#define GBK 16

__global__ __launch_bounds__(256, 2)
void gemm_nt_f32(const float* __restrict__ A, const float* __restrict__ W,
                 float* __restrict__ C, const float* __restrict__ bias,
                 int M, int N, int K)
{
    __shared__ float As[GBK][GBM + 4];   // [kk][m], row stride 132 (16B aligned)
    __shared__ float Ws[GBK][GBN + 1];   // [kk][n], scalar strided reads

    const int tid = threadIdx.x;
    const int tx = tid & 15;             // 16 col-threads
    const int ty = tid >> 4;             // 16 row-threads
    const int m0 = blockIdx.y * GBM;
    const int n0 = blockIdx.x * GBN;

    float acc[8][8];
#pragma unroll
    for (int a = 0; a < 8; ++a)
#pragma unroll
        for (int e = 0; e < 8; ++e) acc[a][e] = 0.f;

    const int lr = tid >> 2;             // 0..63 (row within tile)
    const int lq = tid & 3;              // float4 chunk within 16-wide k

    for (int k0 = 0; k0 < K; k0 += GBK) {
#pragma unroll
        for (int l = 0; l < 2; ++l) {
            const int m = lr + 64 * l;
            float4 va = *reinterpret_cast<const float4*>(&A[(size_t)(m0 + m) * K + k0 + 4 * lq]);
            As[4*lq+0][m] = va.x; As[4*lq+1][m] = va.y;
            As[4*lq+2][m] = va.z; As[4*lq+3][m] = va.w;
            float4 vw = *reinterpret_cast<const float4*>(&W[(size_t)(n0 + m) * K + k0 + 4 * lq]);
            Ws[4*lq+0][m] = vw.x; Ws[4*lq+1][m] = vw.y;
            Ws[4*lq+2][m] = vw.z; Ws[4*lq+3][m] = vw.w;
        }
        __syncthreads();
#pragma unroll
        for (int kk = 0; kk < GBK; ++kk) {
            float av[8], wv[8];
            float4 a0 = *reinterpret_cast<const float4*>(&As[kk][ty * 8]);
            float4 a1 = *reinterpret_cast<const float4*>(&As[kk][ty * 8 + 4]);
            av[0]=a0.x; av[1]=a0.y; av[2]=a0.z; av[3]=a0.w;
            av[4]=a1.x; av[5]=a1.y; av[6]=a1.z; av[7]=a1.w;
#pragma unroll
            for (int e = 0; e < 8; ++e) wv[e] = Ws[kk][tx + 16 * e];  // conflict-free strided
#pragma unroll
            for (int a = 0; a < 8; ++a)
#pragma unroll
                for (int e = 0; e < 8; ++e)
                    acc[a][e] = fmaf(av[a], wv[e], acc[a][e]);
        }
        __syncthreads();
    }

#pragma unroll
    for (int a = 0; a < 8; ++a) {
        const int m = m0 + ty * 8 + a;
#pragma unroll
        for (int e = 0; e < 8; ++e) {
            const int n = n0 + tx + 16 * e;
            float v = acc[a][e];
            if (bias) v += bias[n];
            C[(size_t)m * N + n] = v;
        }
    }
}

// ---------------------------------------------------------------------------
// RoPE in-place on [BS, DMODEL] viewed as [BS, H, 64]. One thread per (bs,h,j)
// pair, j in [0,32): rotates (x_j, x_{j+32}).
// ---------------------------------------------------------------------------
__global__ __launch_bounds__(256)
void rope_inplace(float* __restrict__ X, int total)
{
    int idx = blockIdx.x * 256 + threadIdx.x;
    if (idx >= total) return;
    const int j    = idx & 31;
    const int rest = idx >> 5;
    const int h    = rest & (NHEADS - 1);
    const int bs   = rest >> 4;
    const int pos  = bs & (SS - 1);

    // inv_freq = 10000^{-j/32} computed in double, rounded to fp32 (<=1e-7 rel
    // from the jax fp32 pow chain); angle product in fp32 to mirror jax.
    const double l2_10k_over32 = 13.287712379549449 / 32.0;  // log2(10000)/32
    const float invf = (float)exp2(-(double)j * l2_10k_over32);
    const float ang  = (float)pos * invf;
    const float c  = cosf(ang);
    const float sn = sinf(ang);

    const size_t base = (size_t)bs * DMODEL + h * DK;
    const float x1 = X[base + j];
    const float x2 = X[base + j + 32];
    X[base + j]      = x1 * c - x2 * sn;
    X[base + j + 32] = x2 * c + x1 * sn;
}

// ---------------------------------------------------------------------------
// Fused attention: per block = one (b,h) and 16 q-rows.
//   scores (fp32, Q regs x K LDS tiles) -> softmax (shfl over 32 lanes)
//   -> attn write (fp32, d_out) -> PV (p via LDS, V LDS tiles) -> ctx write.
// 512 threads: r = tid>>5 (q-row 0..15), i = tid&31 (k-lane / d-lane).
// ---------------------------------------------------------------------------
#define QT 16

__global__ __launch_bounds__(512, 1)
void attn_fused(const float* __restrict__ Q, const float* __restrict__ K,
                const float* __restrict__ V, float* __restrict__ attn,
                float* __restrict__ ctx)
{
    __shared__ float Kt[32][68];     // K/V tile (also Q staging), 16B-aligned rows
    __shared__ float Ps[QT][33];     // p redistribution

    const int bh = blockIdx.y;               // b*16 + h
    const int b  = bh >> 4;
    const int h  = bh & 15;
    const int q0 = blockIdx.x * QT;
    const int tid = threadIdx.x;
    const int r = tid >> 5;                  // 0..15
    const int i = tid & 31;                  // 0..31

    const size_t base = ((size_t)b * SS) * DMODEL + h * DK;  // + s*DMODEL + d

    // ---- stage Q tile (16x64) and pull own row into registers ----
    if (tid < 256) {
        const int row = tid >> 4, c = tid & 15;
        *reinterpret_cast<float4*>(&Kt[row][4 * c]) =
            *reinterpret_cast<const float4*>(&Q[base + (size_t)(q0 + row) * DMODEL + 4 * c]);
    }
    __syncthreads();
    float4 q4[16];
#pragma unroll
    for (int c = 0; c < 16; ++c) q4[c] = *reinterpret_cast<const float4*>(&Kt[r][4 * c]);
    __syncthreads();

    // ---- scores: 64 k-tiles of 32 ----
    float p[64];
    const float scale = 0.125f;   // 1/sqrt(64)
#pragma unroll
    for (int jt = 0; jt < 64; ++jt) {
        {   // stage K tile rows [32jt, 32jt+32)
            const int row = tid >> 4, c = tid & 15;
            *reinterpret_cast<float4*>(&Kt[row][4 * c]) =
                *reinterpret_cast<const float4*>(&K[base + (size_t)(32 * jt + row) * DMODEL + 4 * c]);
        }
        __syncthreads();
        float s = 0.f;
#pragma unroll
        for (int c = 0; c < 16; ++c) {
            const float4 kv = *reinterpret_cast<const float4*>(&Kt[i][4 * c]);
            s = fmaf(q4[c].x, kv.x, s); s = fmaf(q4[c].y, kv.y, s);
            s = fmaf(q4[c].z, kv.z, s); s = fmaf(q4[c].w, kv.w, s);
        }
        p[jt] = s * scale;
        __syncthreads();
    }

    // ---- softmax across the 32 lanes sharing row r ----
    float m = -1e30f;
#pragma unroll
    for (int jt = 0; jt < 64; ++jt) m = fmaxf(m, p[jt]);
#pragma unroll
    for (int o = 16; o >= 1; o >>= 1) m = fmaxf(m, __shfl_xor(m, o, 64));
    float sum = 0.f;
#pragma unroll
    for (int jt = 0; jt < 64; ++jt) { p[jt] = expf(p[jt] - m); sum += p[jt]; }
#pragma unroll
    for (int o = 16; o >= 1; o >>= 1) sum += __shfl_xor(sum, o, 64);
    const float rinv = 1.0f / sum;
#pragma unroll
    for (int jt = 0; jt < 64; ++jt) p[jt] *= rinv;

    // ---- write attn rows (fp32, coalesced 128B per 32-lane group) ----
    const size_t arow = ((size_t)bh * SS + q0 + r) * SS + i;
#pragma unroll
    for (int jt = 0; jt < 64; ++jt) attn[arow + 32 * jt] = p[jt];

    // ---- PV: ctx[r][d] for d = i and i+32 ----
    float acc0 = 0.f, acc1 = 0.f;
#pragma unroll
    for (int jt = 0; jt < 64; ++jt) {
        {   // stage V tile rows [32jt, 32jt+32)
            const int row = tid >> 4, c = tid & 15;
            *reinterpret_cast<float4*>(&Kt[row][4 * c]) =
                *reinterpret_cast<const float4*>(&V[base + (size_t)(32 * jt + row) * DMODEL + 4 * c]);
        }
        Ps[r][i] = p[jt];
        __syncthreads();
#pragma unroll
        for (int kk = 0; kk < 32; ++kk) {
            const float pv = Ps[r][kk];              // broadcast
            acc0 = fmaf(pv, Kt[kk][i], acc0);        // conflict-free (pad 68)
            acc1 = fmaf(pv, Kt[kk][i + 32], acc1);
        }
        __syncthreads();
    }
    const size_t cbase = ((size_t)b * SS + q0 + r) * DMODEL + h * DK;
    ctx[cbase + i] = acc0;
    ctx[cbase + i + 32] = acc1;
}

// ---------------------------------------------------------------------------
extern "C" void kernel_launch(void* const* d_in, const int* in_sizes, int n_in,
                              void* d_out, int out_size, void* d_ws, size_t ws_size,
                              hipStream_t stream)
{
    const float* query = (const float*)d_in[0];
    const float* key   = (const float*)d_in[1];
    const float* value = (const float*)d_in[2];
    const float* Wq    = (const float*)d_in[3];
    const float* Wk    = (const float*)d_in[4];
    const float* Wv    = (const float*)d_in[5];
    const float* Wo    = (const float*)d_in[6];
    const float* bo    = (const float*)d_in[7];

    float* out   = (float*)d_out;                          // [B,S,D] = 4.2M floats
    float* attnO = out + (size_t)BSR * DMODEL;             // [B,H,S,S]

    const size_t NPROJ = (size_t)BSR * DMODEL;             // 4.2M floats (16 MB)
    float* Qp  = (float*)d_ws;
    float* Kp  = Qp + NPROJ;
    float* Vp  = Kp + NPROJ;
    float* ctx = Vp + NPROJ;                               // 64 MB total ws

    const dim3 ggrid(DMODEL / GBN, BSR / GBM);             // (8, 32)
    gemm_nt_f32<<<ggrid, 256, 0, stream>>>(query, Wq, Qp, nullptr, BSR, DMODEL, DMODEL);
    gemm_nt_f32<<<ggrid, 256, 0, stream>>>(key,   Wk, Kp, nullptr, BSR, DMODEL, DMODEL);
    gemm_nt_f32<<<ggrid, 256, 0, stream>>>(value, Wv, Vp, nullptr, BSR, DMODEL, DMODEL);

    const int rope_total = BSR * NHEADS * 32;              // 2,097,152
    const int rope_blocks = (rope_total + 255) / 256;
    rope_inplace<<<rope_blocks, 256, 0, stream>>>(Qp, rope_total);
    rope_inplace<<<rope_blocks, 256, 0, stream>>>(Kp, rope_total);

    attn_fused<<<dim3(SS / QT, BB * NHEADS), 512, 0, stream>>>(Qp, Kp, Vp, attnO, ctx);

    gemm_nt_f32<<<ggrid, 256, 0, stream>>>(ctx, Wo, out, bo, BSR, DMODEL, DMODEL);
}

// Round 2
// 1414.405 us; speedup vs baseline: 2.4016x; 2.4016x over previous
//
#include <hip/hip_runtime.h>
#include <cmath>

#define BB 2
#define SS 2048
#define DMODEL 1024
#define NHEADS 16
#define DK 64
#define BSR (BB*SS)          // 4096 rows

typedef float f32x4 __attribute__((ext_vector_type(4)));
typedef short s16x8 __attribute__((ext_vector_type(8)));
#define MFMA_BF16 __builtin_amdgcn_mfma_f32_16x16x32_bf16

__device__ __forceinline__ unsigned short f2bf(float x) {
    unsigned int u = __float_as_uint(x);
    unsigned int r = u + 0x7FFFu + ((u >> 16) & 1u);   // RNE
    return (unsigned short)(r >> 16);
}
__device__ __forceinline__ float bf2f(unsigned short h) {
    return __uint_as_float(((unsigned int)h) << 16);
}

// ---------------------------------------------------------------------------
// GEMM fp32: C=A@W^T. MODE 0: fp32 out (+bias). MODE 1: RoPE + hi/lo bf16
// split, head-major [b][h][s][64] (Q/K). MODE 2: bf16 transpose [b][h][d][s].
// ---------------------------------------------------------------------------
#define GBM 128
#define GBN 128
#define GBK 16

template<int MODE>
__global__ __launch_bounds__(256, 2)
void gemm_nt(const float* __restrict__ A, const float* __restrict__ W,
             float* __restrict__ C, const float* __restrict__ bias,
             unsigned short* __restrict__ O1, unsigned short* __restrict__ O2,
             int M, int N, int K)
{
    __shared__ float As[GBK][GBM + 4];
    __shared__ float Ws[GBK][GBN + 1];

    const int tid = threadIdx.x;
    const int tx = tid & 15;
    const int ty = tid >> 4;
    const int m0 = blockIdx.y * GBM;
    const int n0 = blockIdx.x * GBN;

    float acc[8][8];
#pragma unroll
    for (int a = 0; a < 8; ++a)
#pragma unroll
        for (int e = 0; e < 8; ++e) acc[a][e] = 0.f;

    const int lr = tid >> 2;
    const int lq = tid & 3;

    for (int k0 = 0; k0 < K; k0 += GBK) {
#pragma unroll
        for (int l = 0; l < 2; ++l) {
            const int m = lr + 64 * l;
            float4 va = *reinterpret_cast<const float4*>(&A[(size_t)(m0 + m) * K + k0 + 4 * lq]);
            As[4*lq+0][m] = va.x; As[4*lq+1][m] = va.y;
            As[4*lq+2][m] = va.z; As[4*lq+3][m] = va.w;
            float4 vw = *reinterpret_cast<const float4*>(&W[(size_t)(n0 + m) * K + k0 + 4 * lq]);
            Ws[4*lq+0][m] = vw.x; Ws[4*lq+1][m] = vw.y;
            Ws[4*lq+2][m] = vw.z; Ws[4*lq+3][m] = vw.w;
        }
        __syncthreads();
#pragma unroll
        for (int kk = 0; kk < GBK; ++kk) {
            float av[8], wv[8];
            float4 a0 = *reinterpret_cast<const float4*>(&As[kk][ty * 8]);
            float4 a1 = *reinterpret_cast<const float4*>(&As[kk][ty * 8 + 4]);
            av[0]=a0.x; av[1]=a0.y; av[2]=a0.z; av[3]=a0.w;
            av[4]=a1.x; av[5]=a1.y; av[6]=a1.z; av[7]=a1.w;
#pragma unroll
            for (int e = 0; e < 8; ++e) wv[e] = Ws[kk][tx + 16 * e];
#pragma unroll
            for (int a = 0; a < 8; ++a)
#pragma unroll
                for (int e = 0; e < 8; ++e)
                    acc[a][e] = fmaf(av[a], wv[e], acc[a][e]);
        }
        __syncthreads();
    }

    if constexpr (MODE == 0) {
#pragma unroll
        for (int a = 0; a < 8; ++a) {
            const int m = m0 + ty * 8 + a;
#pragma unroll
            for (int e = 0; e < 8; ++e) {
                const int n = n0 + tx + 16 * e;
                float v = acc[a][e];
                if (bias) v += bias[n];
                C[(size_t)m * N + n] = v;
            }
        }
    } else if constexpr (MODE == 1) {
        // RoPE + split hi/lo. Pairs (e,e+2) for e in {0,1,4,5}: cols j, j+32.
        const double l2_10k_over32 = 13.287712379549449 / 32.0;
        const float invf0 = (float)exp2(-(double)tx * l2_10k_over32);
        const float invf1 = (float)exp2(-(double)(tx + 16) * l2_10k_over32);
#pragma unroll
        for (int a = 0; a < 8; ++a) {
            const int m = m0 + ty * 8 + a;
            const int b = m >> 11;
            const int s = m & (SS - 1);
            const float fs = (float)s;
#pragma unroll
            for (int pi = 0; pi < 4; ++pi) {
                const int ep = (pi < 2) ? pi : pi + 2;        // 0,1,4,5
                const int n = n0 + tx + 16 * ep;
                const int h = n >> 6;
                const int j = tx + 16 * (ep & 1);
                const float invf = (ep & 1) ? invf1 : invf0;
                const float ang = fs * invf;
                const float c = cosf(ang), sn = sinf(ang);
                const float x1 = acc[a][ep], x2 = acc[a][ep + 2];
                const float r1 = x1 * c - x2 * sn;
                const float r2 = x2 * c + x1 * sn;
                const size_t ba = ((size_t)((b << 4) + h) * SS + s) * DK + j;
                const unsigned short u1 = f2bf(r1);
                O1[ba] = u1;        O2[ba]      = f2bf(r1 - bf2f(u1));
                const unsigned short u2 = f2bf(r2);
                O1[ba + 32] = u2;   O2[ba + 32] = f2bf(r2 - bf2f(u2));
            }
        }
    } else {
        // V: bf16, transposed per head: Vt[b][h][d][s]
        const int b  = m0 >> 11;
        const int s0 = (m0 & (SS - 1)) + ty * 8;
#pragma unroll
        for (int e = 0; e < 8; ++e) {
            const int n = n0 + tx + 16 * e;
            const int h = n >> 6;
            const int d = n & 63;
            s16x8 v;
#pragma unroll
            for (int a = 0; a < 8; ++a) v[a] = (short)f2bf(acc[a][e]);
            *reinterpret_cast<s16x8*>(&O1[((size_t)((b << 4) + h) * DK + d) * SS + s0]) = v;
        }
    }
}

// ---------------------------------------------------------------------------
// MFMA attention. Block = (b,h) x 16 q-rows. 512 thr = 8 waves, 256 k each.
// Split-bf16 QK^T -> fp32 softmax (shfl + LDS cross-wave) -> fp32 attn write
// -> bf16 P via swizzled LDS -> PV MFMA -> cross-wave ctx reduce.
// ---------------------------------------------------------------------------
__global__ __launch_bounds__(512)
void attn_mfma(const unsigned short* __restrict__ Qhi, const unsigned short* __restrict__ Qlo,
               const unsigned short* __restrict__ Khi, const unsigned short* __restrict__ Klo,
               const unsigned short* __restrict__ Vt,
               float* __restrict__ attn, float* __restrict__ ctx)
{
    __shared__ __align__(16) char Psm[65536];   // per-wave P (8 KB each) / ctx-reduce overlay
    __shared__ float redm[8][16];
    __shared__ float reds[8][16];
    __shared__ float rinvS[16];

    const int tid   = threadIdx.x;
    const int lane  = tid & 63;
    const int w     = tid >> 6;          // wave 0..7
    const int row16 = lane & 15;
    const int grp   = (lane >> 4) & 3;
    const int bh    = blockIdx.y;        // b*16+h
    const int q0    = blockIdx.x * 16;
    const int kbase = w * 256;

    // ---- Q fragments (A-operand), hi+lo, d-chunks 0/1 ----
    const size_t qoff = ((size_t)bh * SS + q0 + row16) * DK + grp * 8;
    const s16x8 qh0 = *reinterpret_cast<const s16x8*>(Qhi + qoff);
    const s16x8 qh1 = *reinterpret_cast<const s16x8*>(Qhi + qoff + 32);
    const s16x8 ql0 = *reinterpret_cast<const s16x8*>(Qlo + qoff);
    const s16x8 ql1 = *reinterpret_cast<const s16x8*>(Qlo + qoff + 32);

    // ---- scores: 16 tiles of 16 k-cols ----
    f32x4 sc[16];
#pragma unroll
    for (int kt = 0; kt < 16; ++kt) {
        const size_t koff = ((size_t)bh * SS + kbase + kt * 16 + row16) * DK + grp * 8;
        const s16x8 kh0 = *reinterpret_cast<const s16x8*>(Khi + koff);
        const s16x8 kh1 = *reinterpret_cast<const s16x8*>(Khi + koff + 32);
        const s16x8 kl0 = *reinterpret_cast<const s16x8*>(Klo + koff);
        const s16x8 kl1 = *reinterpret_cast<const s16x8*>(Klo + koff + 32);
        f32x4 t = {0.f, 0.f, 0.f, 0.f};
        t = MFMA_BF16(ql0, kh0, t, 0, 0, 0);
        t = MFMA_BF16(ql1, kh1, t, 0, 0, 0);
        t = MFMA_BF16(qh0, kl0, t, 0, 0, 0);
        t = MFMA_BF16(qh1, kl1, t, 0, 0, 0);
        t = MFMA_BF16(qh0, kh0, t, 0, 0, 0);
        t = MFMA_BF16(qh1, kh1, t, 0, 0, 0);
        sc[kt] = t * 0.125f;             // 1/sqrt(64)
    }

    // ---- softmax: rows r_q = grp*4+r, cols spread over 16 lanes ----
    float mr[4] = {-1e30f, -1e30f, -1e30f, -1e30f};
#pragma unroll
    for (int kt = 0; kt < 16; ++kt)
#pragma unroll
        for (int r = 0; r < 4; ++r) mr[r] = fmaxf(mr[r], sc[kt][r]);
#pragma unroll
    for (int off = 1; off < 16; off <<= 1)
#pragma unroll
        for (int r = 0; r < 4; ++r) mr[r] = fmaxf(mr[r], __shfl_xor(mr[r], off, 64));
    if (row16 == 0) {
#pragma unroll
        for (int r = 0; r < 4; ++r) redm[w][grp * 4 + r] = mr[r];
    }
    __syncthreads();
    float gm[4];
#pragma unroll
    for (int r = 0; r < 4; ++r) {
        float v = redm[0][grp * 4 + r];
#pragma unroll
        for (int w2 = 1; w2 < 8; ++w2) v = fmaxf(v, redm[w2][grp * 4 + r]);
        gm[r] = v;
    }

    const float L2E = 1.4426950408889634f;
    float ls[4] = {0.f, 0.f, 0.f, 0.f};
#pragma unroll
    for (int kt = 0; kt < 16; ++kt)
#pragma unroll
        for (int r = 0; r < 4; ++r) {
            const float e = exp2f((sc[kt][r] - gm[r]) * L2E);
            sc[kt][r] = e;
            ls[r] += e;
        }
#pragma unroll
    for (int off = 1; off < 16; off <<= 1)
#pragma unroll
        for (int r = 0; r < 4; ++r) ls[r] += __shfl_xor(ls[r], off, 64);
    if (row16 == 0) {
#pragma unroll
        for (int r = 0; r < 4; ++r) reds[w][grp * 4 + r] = ls[r];
    }
    __syncthreads();
    float rinv[4];
#pragma unroll
    for (int r = 0; r < 4; ++r) {
        float v = 0.f;
#pragma unroll
        for (int w2 = 0; w2 < 8; ++w2) v += reds[w2][grp * 4 + r];
        rinv[r] = 1.0f / v;
    }
    if (w == 0 && row16 == 0) {
#pragma unroll
        for (int r = 0; r < 4; ++r) rinvS[grp * 4 + r] = rinv[r];
    }

    // ---- attn output (fp32, normalized) ----
#pragma unroll
    for (int r = 0; r < 4; ++r) {
        const size_t arow = ((size_t)bh * SS + q0 + grp * 4 + r) * SS + kbase + row16;
#pragma unroll
        for (int kt = 0; kt < 16; ++kt) attn[arow + kt * 16] = sc[kt][r] * rinv[r];
    }

    // ---- P (unnormalized exp, bf16) -> swizzled LDS, C-layout -> A-layout ----
    const int wbase = w * 8192;
#pragma unroll
    for (int kt = 0; kt < 16; ++kt)
#pragma unroll
        for (int r = 0; r < 4; ++r) {
            const int row = grp * 4 + r;
            const int cb  = kt * 32 + row16 * 2;
            const int off = wbase + row * 512 + (cb ^ ((row & 7) << 4));
            *reinterpret_cast<unsigned short*>(Psm + off) = f2bf(sc[kt][r]);
        }
    asm volatile("s_waitcnt lgkmcnt(0)" ::: "memory");

    // ---- PV: acc[dt][r] over this wave's 256 k ----
    s16x8 pf[8];
#pragma unroll
    for (int kc = 0; kc < 8; ++kc) {
        const int cb  = kc * 64 + grp * 16;
        const int off = wbase + row16 * 512 + (cb ^ ((row16 & 7) << 4));
        pf[kc] = *reinterpret_cast<const s16x8*>(Psm + off);
    }
    f32x4 acc[4];
#pragma unroll
    for (int dt = 0; dt < 4; ++dt) acc[dt] = (f32x4){0.f, 0.f, 0.f, 0.f};
#pragma unroll
    for (int dt = 0; dt < 4; ++dt) {
        const size_t vbase = ((size_t)bh * DK + dt * 16 + row16) * SS + kbase + grp * 8;
#pragma unroll
        for (int kc = 0; kc < 8; ++kc) {
            const s16x8 vf = *reinterpret_cast<const s16x8*>(Vt + vbase + kc * 32);
            acc[dt] = MFMA_BF16(pf[kc], vf, acc[dt], 0, 0, 0);
        }
    }

    __syncthreads();     // all P reads done; reuse Psm[0:32K] for ctx reduce
#pragma unroll
    for (int dt = 0; dt < 4; ++dt)
#pragma unroll
        for (int r = 0; r < 4; ++r) {
            const int row = grp * 4 + r;
            *reinterpret_cast<float*>(Psm + w * 4096 + row * 256 + (dt * 16 + row16) * 4) = acc[dt][r];
        }
    __syncthreads();

    const int b = bh >> 4, h = bh & 15;
    for (int o = tid; o < 1024; o += 512) {
        const int q = o >> 6, d = o & 63;
        float s = 0.f;
#pragma unroll
        for (int w2 = 0; w2 < 8; ++w2)
            s += *reinterpret_cast<const float*>(Psm + w2 * 4096 + q * 256 + d * 4);
        ctx[((size_t)b * SS + q0 + q) * DMODEL + h * DK + d] = s * rinvS[q];
    }
}

// ---------------------------------------------------------------------------
extern "C" void kernel_launch(void* const* d_in, const int* in_sizes, int n_in,
                              void* d_out, int out_size, void* d_ws, size_t ws_size,
                              hipStream_t stream)
{
    const float* query = (const float*)d_in[0];
    const float* key   = (const float*)d_in[1];
    const float* value = (const float*)d_in[2];
    const float* Wq    = (const float*)d_in[3];
    const float* Wk    = (const float*)d_in[4];
    const float* Wv    = (const float*)d_in[5];
    const float* Wo    = (const float*)d_in[6];
    const float* bo    = (const float*)d_in[7];

    float* out   = (float*)d_out;
    float* attnO = out + (size_t)BSR * DMODEL;

    const size_t NPROJ = (size_t)BSR * DMODEL;     // 4,194,304
    float* ctx = (float*)d_ws;
    unsigned short* Qhi = (unsigned short*)(ctx + NPROJ);
    unsigned short* Qlo = Qhi + NPROJ;
    unsigned short* Khi = Qlo + NPROJ;
    unsigned short* Klo = Khi + NPROJ;
    unsigned short* Vt  = Klo + NPROJ;

    const dim3 ggrid(DMODEL / GBN, BSR / GBM);     // (8, 32)
    gemm_nt<1><<<ggrid, 256, 0, stream>>>(query, Wq, nullptr, nullptr, Qhi, Qlo, BSR, DMODEL, DMODEL);
    gemm_nt<1><<<ggrid, 256, 0, stream>>>(key,   Wk, nullptr, nullptr, Khi, Klo, BSR, DMODEL, DMODEL);
    gemm_nt<2><<<ggrid, 256, 0, stream>>>(value, Wv, nullptr, nullptr, Vt, nullptr, BSR, DMODEL, DMODEL);

    attn_mfma<<<dim3(SS / 16, BB * NHEADS), 512, 0, stream>>>(Qhi, Qlo, Khi, Klo, Vt, attnO, ctx);

    gemm_nt<0><<<ggrid, 256, 0, stream>>>(ctx, Wo, out, bo, nullptr, nullptr, BSR, DMODEL, DMODEL);
}

// Round 3
// 627.805 us; speedup vs baseline: 5.4106x; 2.2529x over previous
//
#include <hip/hip_runtime.h>
#include <cmath>

#define BB 2
#define SS 2048
#define DMODEL 1024
#define NHEADS 16
#define DK 64
#define BSR (BB*SS)          // 4096 rows

typedef float f32x4 __attribute__((ext_vector_type(4)));
typedef short s16x8 __attribute__((ext_vector_type(8)));
typedef unsigned short ushort_t;
#define MFMA_BF16 __builtin_amdgcn_mfma_f32_16x16x32_bf16

__device__ __forceinline__ unsigned short f2bf(float x) {
    unsigned int u = __float_as_uint(x);
    unsigned int r = u + 0x7FFFu + ((u >> 16) & 1u);   // RNE
    return (unsigned short)(r >> 16);
}
__device__ __forceinline__ float bf2f(unsigned short h) {
    return __uint_as_float(((unsigned int)h) << 16);
}
__device__ __forceinline__ unsigned int pk2(float lo, float hi) {
    return (unsigned int)f2bf(lo) | ((unsigned int)f2bf(hi) << 16);
}

// ---------------------------------------------------------------------------
// split: fp32 -> (hi, lo) bf16 for 3 activation tensors + 4 weight tensors.
// ---------------------------------------------------------------------------
__global__ __launch_bounds__(256)
void split_all(const float* __restrict__ q, const float* __restrict__ k,
               const float* __restrict__ v, const float* __restrict__ wq,
               const float* __restrict__ wk, const float* __restrict__ wv,
               const float* __restrict__ wo,
               ushort_t* qsh, ushort_t* qsl, ushort_t* ksh, ushort_t* ksl,
               ushort_t* vsh, ushort_t* vsl,
               ushort_t* wqh, ushort_t* wql, ushort_t* wkh, ushort_t* wkl,
               ushort_t* wvh, ushort_t* wvl, ushort_t* woh, ushort_t* wol)
{
    int blk = blockIdx.x;
    const float* src; ushort_t* dh; ushort_t* dl;
    if      (blk < 2048) { src = q;  dh = qsh; dl = qsl; }
    else if (blk < 4096) { src = k;  dh = ksh; dl = ksl; blk -= 2048; }
    else if (blk < 6144) { src = v;  dh = vsh; dl = vsl; blk -= 4096; }
    else if (blk < 6656) { src = wq; dh = wqh; dl = wql; blk -= 6144; }
    else if (blk < 7168) { src = wk; dh = wkh; dl = wkl; blk -= 6656; }
    else if (blk < 7680) { src = wv; dh = wvh; dl = wvl; blk -= 7168; }
    else                 { src = wo; dh = woh; dl = wol; blk -= 7680; }
    const size_t off = (size_t)blk * 2048 + threadIdx.x * 8;
    float4 a = *reinterpret_cast<const float4*>(src + off);
    float4 b = *reinterpret_cast<const float4*>(src + off + 4);
    float xs[8] = {a.x, a.y, a.z, a.w, b.x, b.y, b.z, b.w};
    s16x8 hi, lo;
#pragma unroll
    for (int i = 0; i < 8; ++i) {
        unsigned short h = f2bf(xs[i]);
        hi[i] = (short)h;
        lo[i] = (short)f2bf(xs[i] - bf2f(h));
    }
    *reinterpret_cast<s16x8*>(dh + off) = hi;
    *reinterpret_cast<s16x8*>(dl + off) = lo;
}

// ---------------------------------------------------------------------------
// sincos table: tab[s*32+j] = (cos, sin) of s * 10000^{-j/32}
// ---------------------------------------------------------------------------
__global__ __launch_bounds__(256)
void build_tab(float2* __restrict__ tab)
{
    const int t = blockIdx.x * 256 + threadIdx.x;    // 65536
    const int s = t >> 5, j = t & 31;
    const double l2 = 13.287712379549449 / 32.0;     // log2(10000)/32
    const float invf = (float)exp2(-(double)j * l2);
    const float ang = (float)s * invf;
    tab[t] = make_float2(cosf(ang), sinf(ang));
}

// ---------------------------------------------------------------------------
// Split-bf16 MFMA GEMM: C[M=4096,N=1024] = A @ W^T, 3-term hi/lo.
// Tile 128(M) x 64(N) x 64(K), 256 thr = 4 waves stacked along M (32 rows ea).
// MODE 0: fp32 out + bias. MODE 1: RoPE + hi/lo split, head-major [bh][s][64].
// MODE 2: bf16 transpose per head: Vt[bh][d][s].
// ---------------------------------------------------------------------------
template<int MODE>
__global__ __launch_bounds__(256)
void gemm_mfma(const ushort_t* __restrict__ Ah, const ushort_t* __restrict__ Al,
               const ushort_t* __restrict__ Bh, const ushort_t* __restrict__ Bl,
               float* __restrict__ outF, const float* __restrict__ bias,
               ushort_t* __restrict__ O1, ushort_t* __restrict__ O2,
               const float2* __restrict__ tab)
{
    __shared__ __align__(16) ushort_t smAh[128 * 64];
    __shared__ __align__(16) ushort_t smAl[128 * 64];
    __shared__ __align__(16) ushort_t smBh[64 * 64];
    __shared__ __align__(16) ushort_t smBl[64 * 64];

    const int tid = threadIdx.x;
    const int lane = tid & 63;
    const int w = tid >> 6;              // wave 0..3
    const int lane16 = lane & 15;
    const int grp = (lane >> 4) & 3;
    const int m0 = blockIdx.y * 128;
    const int n0 = blockIdx.x * 64;
    const int K = 1024;

    f32x4 acc[2][4];
#pragma unroll
    for (int a = 0; a < 2; ++a)
#pragma unroll
        for (int e = 0; e < 4; ++e) acc[a][e] = (f32x4){0.f, 0.f, 0.f, 0.f};

    for (int k0 = 0; k0 < K; k0 += 64) {
        // ---- stage (reg-staged, XOR-slot-swizzled LDS dest) ----
#pragma unroll
        for (int i = 0; i < 4; ++i) {
            const int c = tid + 256 * i;          // 1024 chunks of 16B
            const int row = c >> 3, gs = c & 7;
            const int dst = row * 64 + ((gs ^ (row & 7)) * 8);
            const size_t src = (size_t)(m0 + row) * K + k0 + gs * 8;
            *reinterpret_cast<s16x8*>(&smAh[dst]) = *reinterpret_cast<const s16x8*>(&Ah[src]);
            *reinterpret_cast<s16x8*>(&smAl[dst]) = *reinterpret_cast<const s16x8*>(&Al[src]);
        }
#pragma unroll
        for (int i = 0; i < 2; ++i) {
            const int c = tid + 256 * i;          // 512 chunks
            const int row = c >> 3, gs = c & 7;
            const int dst = row * 64 + ((gs ^ (row & 7)) * 8);
            const size_t src = (size_t)(n0 + row) * K + k0 + gs * 8;
            *reinterpret_cast<s16x8*>(&smBh[dst]) = *reinterpret_cast<const s16x8*>(&Bh[src]);
            *reinterpret_cast<s16x8*>(&smBl[dst]) = *reinterpret_cast<const s16x8*>(&Bl[src]);
        }
        __syncthreads();
#pragma unroll
        for (int ks = 0; ks < 2; ++ks) {
            const int slotk = ks * 4 + grp;
            s16x8 afh[2], afl[2], bfh[4], bfl[4];
#pragma unroll
            for (int mt = 0; mt < 2; ++mt) {
                const int row = w * 32 + mt * 16 + lane16;
                const int off = row * 64 + ((slotk ^ (row & 7)) * 8);
                afh[mt] = *reinterpret_cast<const s16x8*>(&smAh[off]);
                afl[mt] = *reinterpret_cast<const s16x8*>(&smAl[off]);
            }
#pragma unroll
            for (int nt = 0; nt < 4; ++nt) {
                const int row = nt * 16 + lane16;
                const int off = row * 64 + ((slotk ^ (row & 7)) * 8);
                bfh[nt] = *reinterpret_cast<const s16x8*>(&smBh[off]);
                bfl[nt] = *reinterpret_cast<const s16x8*>(&smBl[off]);
            }
#pragma unroll
            for (int mt = 0; mt < 2; ++mt)
#pragma unroll
                for (int nt = 0; nt < 4; ++nt) {
                    acc[mt][nt] = MFMA_BF16(afh[mt], bfl[nt], acc[mt][nt], 0, 0, 0);
                    acc[mt][nt] = MFMA_BF16(afl[mt], bfh[nt], acc[mt][nt], 0, 0, 0);
                    acc[mt][nt] = MFMA_BF16(afh[mt], bfh[nt], acc[mt][nt], 0, 0, 0);
                }
        }
        __syncthreads();
    }

    // ---- epilogues: C[m][n], m = m0+32w+16mt+4grp+r, n = n0+16nt+lane16 ----
    if constexpr (MODE == 0) {
#pragma unroll
        for (int mt = 0; mt < 2; ++mt)
#pragma unroll
            for (int r = 0; r < 4; ++r) {
                const int m = m0 + w * 32 + mt * 16 + grp * 4 + r;
#pragma unroll
                for (int nt = 0; nt < 4; ++nt) {
                    const int n = n0 + nt * 16 + lane16;
                    outF[(size_t)m * 1024 + n] = acc[mt][nt][r] + bias[n];
                }
            }
    } else if constexpr (MODE == 1) {
        const int hh = blockIdx.x;               // head (N-tile == one head)
#pragma unroll
        for (int mt = 0; mt < 2; ++mt)
#pragma unroll
            for (int r = 0; r < 4; ++r) {
                const int m = m0 + w * 32 + mt * 16 + grp * 4 + r;
                const int b = m >> 11, s = m & (SS - 1);
                const size_t base = ((size_t)(b * 16 + hh) * SS + s) * DK;
#pragma unroll
                for (int ntp = 0; ntp < 2; ++ntp) {
                    const int j = ntp * 16 + lane16;          // 0..31
                    const float2 cs = tab[s * 32 + j];
                    const float x1 = acc[mt][ntp][r], x2 = acc[mt][ntp + 2][r];
                    const float r1 = x1 * cs.x - x2 * cs.y;
                    const float r2 = x2 * cs.x + x1 * cs.y;
                    const unsigned short h1 = f2bf(r1);
                    O1[base + j] = h1;       O2[base + j] = f2bf(r1 - bf2f(h1));
                    const unsigned short h2 = f2bf(r2);
                    O1[base + j + 32] = h2;  O2[base + j + 32] = f2bf(r2 - bf2f(h2));
                }
            }
    } else {
        const int hh = blockIdx.x;
#pragma unroll
        for (int mt = 0; mt < 2; ++mt)
#pragma unroll
            for (int r = 0; r < 4; ++r) {
                const int m = m0 + w * 32 + mt * 16 + grp * 4 + r;
                const int b = m >> 11, s = m & (SS - 1);
#pragma unroll
                for (int nt = 0; nt < 4; ++nt) {
                    const int d = nt * 16 + lane16;
                    O1[((size_t)(b * 16 + hh) * DK + d) * SS + s] = f2bf(acc[mt][nt][r]);
                }
            }
    }
}

// ---------------------------------------------------------------------------
// MFMA attention, swapped-operand QK^T + in-register P^T redistribution.
// Block = (b,h) x 16 q-rows, 8 waves, wave w owns k-slice [256w, 256w+256).
// Lane: q = lane&15, grp = (lane>>4)&3.
// sc[kt][r] = S[k = 256w + 16kt + 4grp + r][q]  (64 scores, all same q).
// ---------------------------------------------------------------------------
__global__ __launch_bounds__(512, 4)
void attn_v3(const ushort_t* __restrict__ Qhi, const ushort_t* __restrict__ Qlo,
             const ushort_t* __restrict__ Khi, const ushort_t* __restrict__ Klo,
             const ushort_t* __restrict__ Vt,
             float* __restrict__ attn, ushort_t* __restrict__ ctxh, ushort_t* __restrict__ ctxl)
{
    __shared__ float redm[8][16];
    __shared__ float reds[8][16];
    __shared__ float rinvS[16];
    __shared__ float ctxred[8 * 16 * 69];    // [w][q][d], stride 69 (~34.5 KB)

    const int tid = threadIdx.x;
    const int lane = tid & 63;
    const int w = tid >> 6;
    const int lane16 = lane & 15;            // q within tile
    const int grp = (lane >> 4) & 3;
    const int bh = blockIdx.y;
    const int q0 = blockIdx.x * 16;
    const int kbase = w * 256;

    // ---- Q fragments (B-operand: lane holds Q[q][grp*8+j]) ----
    const size_t qoff = ((size_t)bh * SS + q0 + lane16) * DK + grp * 8;
    const s16x8 qh0 = *reinterpret_cast<const s16x8*>(Qhi + qoff);
    const s16x8 qh1 = *reinterpret_cast<const s16x8*>(Qhi + qoff + 32);
    const s16x8 ql0 = *reinterpret_cast<const s16x8*>(Qlo + qoff);
    const s16x8 ql1 = *reinterpret_cast<const s16x8*>(Qlo + qoff + 32);

    // ---- QK^T: C' = K . Q^T (A-operand = K rows; barrier-free loop) ----
    f32x4 sc[16];
#pragma unroll
    for (int kt = 0; kt < 16; ++kt) {
        const size_t koff = ((size_t)bh * SS + kbase + kt * 16 + lane16) * DK + grp * 8;
        const s16x8 kh0 = *reinterpret_cast<const s16x8*>(Khi + koff);
        const s16x8 kh1 = *reinterpret_cast<const s16x8*>(Khi + koff + 32);
        const s16x8 kl0 = *reinterpret_cast<const s16x8*>(Klo + koff);
        const s16x8 kl1 = *reinterpret_cast<const s16x8*>(Klo + koff + 32);
        f32x4 t = {0.f, 0.f, 0.f, 0.f};
        t = MFMA_BF16(kh0, ql0, t, 0, 0, 0);
        t = MFMA_BF16(kh1, ql1, t, 0, 0, 0);
        t = MFMA_BF16(kl0, qh0, t, 0, 0, 0);
        t = MFMA_BF16(kl1, qh1, t, 0, 0, 0);
        t = MFMA_BF16(kh0, qh0, t, 0, 0, 0);
        t = MFMA_BF16(kh1, qh1, t, 0, 0, 0);
        sc[kt] = t * 0.125f;                 // 1/sqrt(64)
    }

    // ---- softmax over k for this lane's q ----
    float mx = -1e30f;
#pragma unroll
    for (int kt = 0; kt < 16; ++kt)
#pragma unroll
        for (int r = 0; r < 4; ++r) mx = fmaxf(mx, sc[kt][r]);
    mx = fmaxf(mx, __shfl_xor(mx, 16, 64));
    mx = fmaxf(mx, __shfl_xor(mx, 32, 64));
    if (grp == 0) redm[w][lane16] = mx;
    __syncthreads();
    float gm = redm[0][lane16];
#pragma unroll
    for (int w2 = 1; w2 < 8; ++w2) gm = fmaxf(gm, redm[w2][lane16]);

    const float L2E = 1.4426950408889634f;
    float ls = 0.f;
#pragma unroll
    for (int kt = 0; kt < 16; ++kt)
#pragma unroll
        for (int r = 0; r < 4; ++r) {
            const float e = exp2f((sc[kt][r] - gm) * L2E);
            sc[kt][r] = e;                   // unnormalized
            ls += e;
        }
    ls += __shfl_xor(ls, 16, 64);
    ls += __shfl_xor(ls, 32, 64);
    if (grp == 0) reds[w][lane16] = ls;
    __syncthreads();
    float tot = 0.f;
#pragma unroll
    for (int w2 = 0; w2 < 8; ++w2) tot += reds[w2][lane16];
    const float rinv = 1.0f / tot;
    if (tid < 16) rinvS[tid] = rinv;         // lane16==tid, grp==0, w==0

    // ---- attn output (fp32, normalized) ----
    const size_t arow = ((size_t)bh * SS + q0 + lane16) * SS + kbase;
#pragma unroll
    for (int kt = 0; kt < 16; ++kt)
#pragma unroll
        for (int r = 0; r < 4; ++r)
            attn[arow + kt * 16 + grp * 4 + r] = sc[kt][r] * rinv;

    // ---- PV: ctx^T[d][q] += V^T . P^T, P^T built in-register via shfl ----
    f32x4 acc[4];
#pragma unroll
    for (int dt = 0; dt < 4; ++dt) acc[dt] = (f32x4){0.f, 0.f, 0.f, 0.f};

    const int src0 = lane16 + ((grp & 1) << 5);   // q + 32*(g&1)
    const int src1 = src0 + 16;
    const bool sel = (grp >> 1) != 0;
#pragma unroll
    for (int st = 0; st < 8; ++st) {
        const unsigned int A0 = pk2(sc[2 * st][0],     sc[2 * st][1]);
        const unsigned int A1 = pk2(sc[2 * st][2],     sc[2 * st][3]);
        const unsigned int B0 = pk2(sc[2 * st + 1][0], sc[2 * st + 1][1]);
        const unsigned int B1 = pk2(sc[2 * st + 1][2], sc[2 * st + 1][3]);
        const unsigned int d0a = (unsigned int)__shfl((int)A0, src0, 64);
        const unsigned int d0b = (unsigned int)__shfl((int)B0, src0, 64);
        const unsigned int d1a = (unsigned int)__shfl((int)A1, src0, 64);
        const unsigned int d1b = (unsigned int)__shfl((int)B1, src0, 64);
        const unsigned int d2a = (unsigned int)__shfl((int)A0, src1, 64);
        const unsigned int d2b = (unsigned int)__shfl((int)B0, src1, 64);
        const unsigned int d3a = (unsigned int)__shfl((int)A1, src1, 64);
        const unsigned int d3b = (unsigned int)__shfl((int)B1, src1, 64);
        union { unsigned int u[4]; s16x8 v; } bf;
        bf.u[0] = sel ? d0b : d0a;
        bf.u[1] = sel ? d1b : d1a;
        bf.u[2] = sel ? d2b : d2a;
        bf.u[3] = sel ? d3b : d3a;
#pragma unroll
        for (int dt = 0; dt < 4; ++dt) {
            const s16x8 vf = *reinterpret_cast<const s16x8*>(
                &Vt[((size_t)bh * DK + dt * 16 + lane16) * SS + kbase + st * 32 + grp * 8]);
            acc[dt] = MFMA_BF16(vf, bf.v, acc[dt], 0, 0, 0);
        }
    }

    // ---- cross-wave ctx reduce; write ctx pre-split hi/lo ----
#pragma unroll
    for (int dt = 0; dt < 4; ++dt)
#pragma unroll
        for (int r = 0; r < 4; ++r)
            ctxred[w * 1104 + lane16 * 69 + dt * 16 + grp * 4 + r] = acc[dt][r];
    __syncthreads();

    const int b = bh >> 4, h = bh & 15;
    for (int o = tid; o < 1024; o += 512) {
        const int q = o >> 6, d = o & 63;
        float ssum = 0.f;
#pragma unroll
        for (int w2 = 0; w2 < 8; ++w2) ssum += ctxred[w2 * 1104 + q * 69 + d];
        ssum *= rinvS[q];
        const size_t co = ((size_t)b * SS + q0 + q) * DMODEL + h * DK + d;
        const unsigned short hi = f2bf(ssum);
        ctxh[co] = hi;
        ctxl[co] = f2bf(ssum - bf2f(hi));
    }
}

// ---------------------------------------------------------------------------
extern "C" void kernel_launch(void* const* d_in, const int* in_sizes, int n_in,
                              void* d_out, int out_size, void* d_ws, size_t ws_size,
                              hipStream_t stream)
{
    const float* query = (const float*)d_in[0];
    const float* key   = (const float*)d_in[1];
    const float* value = (const float*)d_in[2];
    const float* Wq    = (const float*)d_in[3];
    const float* Wk    = (const float*)d_in[4];
    const float* Wv    = (const float*)d_in[5];
    const float* Wo    = (const float*)d_in[6];
    const float* bo    = (const float*)d_in[7];

    float* out   = (float*)d_out;
    float* attnO = out + (size_t)BSR * DMODEL;

    const size_t NPROJ = (size_t)BSR * DMODEL;      // 4,194,304
    const size_t NW    = (size_t)DMODEL * DMODEL;   // 1,048,576

    char* p = (char*)d_ws;
    float2* tab = (float2*)p;                 p += 1 << 20;          // 0.5MB used
    ushort_t* qsh = (ushort_t*)p;             p += NPROJ * 2;
    ushort_t* qsl = (ushort_t*)p;             p += NPROJ * 2;
    ushort_t* ksh = (ushort_t*)p;             p += NPROJ * 2;
    ushort_t* ksl = (ushort_t*)p;             p += NPROJ * 2;
    ushort_t* vsh = (ushort_t*)p;             p += NPROJ * 2;
    ushort_t* vsl = (ushort_t*)p;             p += NPROJ * 2;
    ushort_t* wqh = (ushort_t*)p;             p += NW * 2;
    ushort_t* wql = (ushort_t*)p;             p += NW * 2;
    ushort_t* wkh = (ushort_t*)p;             p += NW * 2;
    ushort_t* wkl = (ushort_t*)p;             p += NW * 2;
    ushort_t* wvh = (ushort_t*)p;             p += NW * 2;
    ushort_t* wvl = (ushort_t*)p;             p += NW * 2;
    ushort_t* woh = (ushort_t*)p;             p += NW * 2;
    ushort_t* wol = (ushort_t*)p;             p += NW * 2;
    ushort_t* Vt  = (ushort_t*)p;             p += NPROJ * 2;
    // Aliases (sequential lifetimes): Q-GEMM out <- vs buffers (vs dead after
    // V-GEMM); K-GEMM out <- qs buffers; attn ctx out <- ks buffers.
    ushort_t* Qhi = vsh; ushort_t* Qlo = vsl;
    ushort_t* Khi = qsh; ushort_t* Klo = qsl;
    ushort_t* ctxhC = ksh; ushort_t* ctxlC = ksl;

    split_all<<<8192, 256, 0, stream>>>(query, key, value, Wq, Wk, Wv, Wo,
                                        qsh, qsl, ksh, ksl, vsh, vsl,
                                        wqh, wql, wkh, wkl, wvh, wvl, woh, wol);
    build_tab<<<256, 256, 0, stream>>>(tab);

    const dim3 ggrid(DMODEL / 64, BSR / 128);       // (16, 32)
    gemm_mfma<2><<<ggrid, 256, 0, stream>>>(vsh, vsl, wvh, wvl, nullptr, nullptr, Vt, nullptr, nullptr);
    gemm_mfma<1><<<ggrid, 256, 0, stream>>>(qsh, qsl, wqh, wql, nullptr, nullptr, Qhi, Qlo, tab);
    gemm_mfma<1><<<ggrid, 256, 0, stream>>>(ksh, ksl, wkh, wkl, nullptr, nullptr, Khi, Klo, tab);

    attn_v3<<<dim3(SS / 16, BB * NHEADS), 512, 0, stream>>>(Qhi, Qlo, Khi, Klo, Vt,
                                                            attnO, ctxhC, ctxlC);

    gemm_mfma<0><<<ggrid, 256, 0, stream>>>(ctxhC, ctxlC, woh, wol, out, bo, nullptr, nullptr, nullptr);
}